// Round 3
// baseline (1797.997 us; speedup 1.0000x reference)
//
#include <hip/hip_runtime.h>
#include <stdint.h>

#define T_TOK 1024
#define HD 2880
#define ID 2880
#define NE 16
#define NTOP 4

#define BM 128
#define BN 64
#define BK 64
#define NKT (HD / BK)        // 45
#define NIB (ID / BN)        // 45
#define NMB (T_TOK / BM)     // 8
#define NB1 (NE * NIB * NMB) // 5760

typedef short bf16x8 __attribute__((ext_vector_type(8)));
typedef float f32x4 __attribute__((ext_vector_type(4)));

// fp32 -> bf16 (RNE) via native __bf16 cast (v_cvt_pk_bf16_f32)
__device__ __forceinline__ uint4 pack8f(const float* v) {
    union { __bf16 b[8]; uint4 q; } p;
#pragma unroll
    for (int j = 0; j < 8; j++) p.b[j] = (__bf16)v[j];
    return p.q;
}
__device__ __forceinline__ unsigned short bf16bits(float f) {
    union { __bf16 b[2]; unsigned short u[2]; } p;
    p.b[0] = (__bf16)f;
    return p.u[0];
}

// ---------------- init: zero output + counts ----------------
__global__ __launch_bounds__(256) void k_init(float* __restrict__ out, int* __restrict__ cnt) {
    int i = blockIdx.x * 256 + threadIdx.x;
    ((float4*)out)[i] = make_float4(0.f, 0.f, 0.f, 0.f);
    if (blockIdx.x == 0 && threadIdx.x < NE) cnt[threadIdx.x] = 0;
}

// ---------------- x -> bf16 pre-pass ----------------
__global__ __launch_bounds__(256) void k_xbf(const float* __restrict__ x, unsigned short* __restrict__ xbf) {
    const size_t i = (size_t)blockIdx.x * 256 + threadIdx.x;   // 8 floats each
    float v[8];
    float4 a = ((const float4*)x)[i * 2];
    float4 b = ((const float4*)x)[i * 2 + 1];
    v[0] = a.x; v[1] = a.y; v[2] = a.z; v[3] = a.w;
    v[4] = b.x; v[5] = b.y; v[6] = b.z; v[7] = b.w;
    ((uint4*)xbf)[i] = pack8f(v);
}

// ---------------- router ----------------
__global__ __launch_bounds__(256) void k_router(
    const float* __restrict__ x, const float* __restrict__ rw, const float* __restrict__ rb,
    float* __restrict__ topw, int* __restrict__ cnt, int* __restrict__ list)
{
    const int t = blockIdx.x;
    const int tid = threadIdx.x;
    float acc[NE];
#pragma unroll
    for (int e = 0; e < NE; e++) acc[e] = 0.f;
    for (int c = tid; c < HD; c += 256) {
        float xv = x[(size_t)t * HD + c];
#pragma unroll
        for (int e = 0; e < NE; e++) acc[e] += xv * rw[(size_t)e * HD + c];
    }
    __shared__ float red[4][NE];
    const int lane = tid & 63, wv = tid >> 6;
#pragma unroll
    for (int e = 0; e < NE; e++) {
        float v = acc[e];
#pragma unroll
        for (int off = 32; off > 0; off >>= 1) v += __shfl_down(v, off, 64);
        if (lane == 0) red[wv][e] = v;
    }
    __syncthreads();
    if (tid == 0) {
        float p[NE];
        float mx = -1e30f;
        for (int e = 0; e < NE; e++) {
            float v = red[0][e] + red[1][e] + red[2][e] + red[3][e] + rb[e];
            p[e] = v; mx = fmaxf(mx, v);
        }
        for (int e = 0; e < NE; e++) p[e] = expf(p[e] - mx);
        int sel[NTOP]; float pw[NTOP]; float ssum = 0.f;
        for (int k = 0; k < NTOP; k++) {
            float best = -1.f; int bi = 0;
            for (int e = 0; e < NE; e++)
                if (p[e] > best) { best = p[e]; bi = e; }
            sel[k] = bi; pw[k] = best; ssum += best; p[bi] = -2.f;
        }
        for (int k = 0; k < NTOP; k++) {
            topw[t * NTOP + k] = pw[k] / ssum;
            int e = sel[k];
            int pos = atomicAdd(&cnt[e], 1);
            list[e * T_TOK + pos] = t * NTOP + k;
        }
    }
}

// ---------------- prefix scan ----------------
__global__ void k_scan(const int* __restrict__ cnt, int* __restrict__ offs) {
    if (threadIdx.x == 0 && blockIdx.x == 0) {
        int s = 0;
        for (int e = 0; e < NE; e++) { offs[e] = s; s += cnt[e]; }
        offs[NE] = s;
    }
}

// ---------------- GEMM1: A direct from global (bf16), W double-buffered in LDS ----------------
__global__ __launch_bounds__(512, 6) void k_gemm1(
    const unsigned short* __restrict__ xbf,
    const float* __restrict__ wg, const float* __restrict__ bg,
    const float* __restrict__ wu, const float* __restrict__ bu,
    const int* __restrict__ cnt, const int* __restrict__ offs,
    const int* __restrict__ list,
    unsigned short* __restrict__ act)
{
    const int lin = blockIdx.x;
    const int logical = (lin & 7) * (NB1 / 8) + (lin >> 3);
    const int mblk = logical & 7;
    const int iblk = (logical >> 3) % NIB;
    const int e = logical / (NIB * NMB);

    const int count = cnt[e];
    const int m0 = mblk * BM;
    if (m0 >= count) return;
    const int mcount = min(BM, count - m0);
    const int i0 = iblk * BN;
    const int tid = threadIdx.x;

    __shared__ char sG[2][BN * BK * 2];   // 8 KB x2
    __shared__ char sU[2][BN * BK * 2];   // 8 KB x2
    __shared__ int lidx[BM];

    if (tid < BM) lidx[tid] = list[e * T_TOK + m0 + min(tid, mcount - 1)];

    // W staging: tid<256 -> gate, else up; per thread 16 strided floats
    const int wtid = tid & 255;
    const int wc = wtid & 63, whg = wtid >> 6;
    const float* wsrc = (tid < 256 ? wg : wu) + ((size_t)e * HD + whg * 16) * ID + i0 + wc;
    char* const wb0 = (tid < 256 ? sG[0] : sU[0]);
    char* const wb1 = (tid < 256 ? sG[1] : sU[1]);

    const int lane = tid & 63, wid = tid >> 6;
    const int wm = wid >> 1, wn = wid & 1;
    const int lr = lane & 15, lk = lane >> 4;

    float rwv[16];
#define LOADW1(kt_) { _Pragma("unroll") \
        for (int j_ = 0; j_ < 16; j_++) rwv[j_] = wsrc[(size_t)((kt_) * BK + j_) * ID]; }
#define STOREW1(dst_) { \
        *(uint4*)((dst_) + wc * 128 + (((whg * 2) ^ (wc & 7)) * 16)) = pack8f(rwv); \
        *(uint4*)((dst_) + wc * 128 + (((whg * 2 + 1) ^ (wc & 7)) * 16)) = pack8f(rwv + 8); }

    LOADW1(0);
    __syncthreads();   // lidx visible
    const unsigned short* arow0 = xbf + (size_t)(lidx[wm * 32 + lr] >> 2) * HD;
    const unsigned short* arow1 = xbf + (size_t)(lidx[wm * 32 + 16 + lr] >> 2) * HD;
    STOREW1(wb0);
    __syncthreads();

    f32x4 accG[2][2], accU[2][2];
#pragma unroll
    for (int mb = 0; mb < 2; mb++)
#pragma unroll
        for (int cb = 0; cb < 2; cb++) {
            accG[mb][cb] = (f32x4){0.f, 0.f, 0.f, 0.f};
            accU[mb][cb] = (f32x4){0.f, 0.f, 0.f, 0.f};
        }

    for (int kt = 0; kt < NKT; kt++) {
        const bool more = (kt + 1 < NKT);
        if (more) LOADW1(kt + 1);                 // weight prefetch in flight
        bf16x8 af[2][2];
#pragma unroll
        for (int ks = 0; ks < 2; ks++) {
            const int koff = kt * BK + (ks * 4 + lk) * 8;
            af[ks][0] = *(const bf16x8*)(arow0 + koff);
            af[ks][1] = *(const bf16x8*)(arow1 + koff);
        }
        const char* cG = sG[kt & 1];
        const char* cU = sU[kt & 1];
#pragma unroll
        for (int ks = 0; ks < 2; ks++) {
            const int s = ks * 4 + lk;
#pragma unroll
            for (int cb = 0; cb < 2; cb++) {
                const int ii = wn * 32 + cb * 16 + lr;
                bf16x8 gf = *(const bf16x8*)(cG + ii * 128 + ((s ^ (ii & 7)) * 16));
                accG[0][cb] = __builtin_amdgcn_mfma_f32_16x16x32_bf16(af[ks][0], gf, accG[0][cb], 0, 0, 0);
                accG[1][cb] = __builtin_amdgcn_mfma_f32_16x16x32_bf16(af[ks][1], gf, accG[1][cb], 0, 0, 0);
                bf16x8 uf = *(const bf16x8*)(cU + ii * 128 + ((s ^ (ii & 7)) * 16));
                accU[0][cb] = __builtin_amdgcn_mfma_f32_16x16x32_bf16(af[ks][0], uf, accU[0][cb], 0, 0, 0);
                accU[1][cb] = __builtin_amdgcn_mfma_f32_16x16x32_bf16(af[ks][1], uf, accU[1][cb], 0, 0, 0);
            }
        }
        if (more) { STOREW1(((kt & 1) ? wb0 : wb1)); }
        __syncthreads();
    }
#undef LOADW1
#undef STOREW1

    const int gbase = offs[e] + m0;
#pragma unroll
    for (int mb = 0; mb < 2; mb++)
#pragma unroll
        for (int cb = 0; cb < 2; cb++) {
            const int col = i0 + wn * 32 + cb * 16 + lr;
            const float bgv = bg[e * ID + col];
            const float buv = bu[e * ID + col];
#pragma unroll
            for (int q = 0; q < 4; q++) {
                const int r = wm * 32 + mb * 16 + lk * 4 + q;
                if (r < mcount) {
                    float gv = fminf(accG[mb][cb][q] + bgv, 7.0f);
                    float uv = fminf(fmaxf(accU[mb][cb][q] + buv, -7.0f), 7.0f);
                    float av = (uv + 1.0f) * (gv / (1.0f + __expf(-1.702f * gv)));
                    act[(size_t)(gbase + r) * ID + col] = bf16bits(av);
                }
            }
        }
}

// ---------------- GEMM2: A direct from act, W double-buffered in LDS ----------------
__global__ __launch_bounds__(512, 8) void k_gemm2(
    const unsigned short* __restrict__ act,
    const float* __restrict__ wd, const float* __restrict__ bd,
    const float* __restrict__ topw,
    const int* __restrict__ cnt, const int* __restrict__ offs,
    const int* __restrict__ list,
    float* __restrict__ out)
{
    const int lin = blockIdx.x;
    const int logical = (lin & 7) * (NB1 / 8) + (lin >> 3);
    const int mblk = logical & 7;
    const int hblk = (logical >> 3) % NIB;
    const int e = logical / (NIB * NMB);

    const int count = cnt[e];
    const int m0 = mblk * BM;
    if (m0 >= count) return;
    const int mcount = min(BM, count - m0);
    const int h0 = hblk * BN;
    const int tid = threadIdx.x;
    const int gbase = offs[e] + m0;

    __shared__ char sW[2][BN * BK * 2];   // 8 KB x2
    __shared__ int lidx[BM];

    if (tid < BM) lidx[tid] = list[e * T_TOK + m0 + min(tid, mcount - 1)];

    // W staging: 512 threads, 8 strided floats each (k = whg*8 + j)
    const int wc = tid & 63, whg = tid >> 6;
    const float* wsrc = wd + (size_t)e * ID * HD + (size_t)(whg * 8) * HD + h0 + wc;

    const int lane = tid & 63, wid = tid >> 6;
    const int wm = wid >> 1, wn = wid & 1;
    const int lr = lane & 15, lk = lane >> 4;

    float rwv[8];
#define LOADW2(kt_) { _Pragma("unroll") \
        for (int j_ = 0; j_ < 8; j_++) rwv[j_] = wsrc[(size_t)((kt_) * BK + j_) * HD]; }
#define STOREW2(dst_) { \
        *(uint4*)((dst_) + wc * 128 + ((whg ^ (wc & 7)) * 16)) = pack8f(rwv); }

    LOADW2(0);
    __syncthreads();   // lidx visible
    const int r0 = gbase + min(wm * 32 + lr, mcount - 1);
    const int r1 = gbase + min(wm * 32 + 16 + lr, mcount - 1);
    const unsigned short* arow0 = act + (size_t)r0 * ID;
    const unsigned short* arow1 = act + (size_t)r1 * ID;
    STOREW2(sW[0]);
    __syncthreads();

    f32x4 acc[2][2];
#pragma unroll
    for (int mb = 0; mb < 2; mb++)
#pragma unroll
        for (int cb = 0; cb < 2; cb++) acc[mb][cb] = (f32x4){0.f, 0.f, 0.f, 0.f};

    for (int kt = 0; kt < NKT; kt++) {
        const bool more = (kt + 1 < NKT);
        if (more) LOADW2(kt + 1);
        bf16x8 af[2][2];
#pragma unroll
        for (int ks = 0; ks < 2; ks++) {
            const int koff = kt * BK + (ks * 4 + lk) * 8;
            af[ks][0] = *(const bf16x8*)(arow0 + koff);
            af[ks][1] = *(const bf16x8*)(arow1 + koff);
        }
        const char* cW = sW[kt & 1];
#pragma unroll
        for (int ks = 0; ks < 2; ks++) {
            const int s = ks * 4 + lk;
#pragma unroll
            for (int cb = 0; cb < 2; cb++) {
                const int ii = wn * 32 + cb * 16 + lr;
                bf16x8 wf = *(const bf16x8*)(cW + ii * 128 + ((s ^ (ii & 7)) * 16));
                acc[0][cb] = __builtin_amdgcn_mfma_f32_16x16x32_bf16(af[ks][0], wf, acc[0][cb], 0, 0, 0);
                acc[1][cb] = __builtin_amdgcn_mfma_f32_16x16x32_bf16(af[ks][1], wf, acc[1][cb], 0, 0, 0);
            }
        }
        if (more) { STOREW2(((kt & 1) ? sW[0] : sW[1])); }
        __syncthreads();
    }
#undef LOADW2
#undef STOREW2

#pragma unroll
    for (int mb = 0; mb < 2; mb++)
#pragma unroll
        for (int cb = 0; cb < 2; cb++) {
            const int col = h0 + wn * 32 + cb * 16 + lr;
            const float bdv = bd[e * HD + col];
#pragma unroll
            for (int q = 0; q < 4; q++) {
                const int r = wm * 32 + mb * 16 + lk * 4 + q;
                if (r < mcount) {
                    int idx = lidx[r];
                    float w = topw[idx];
                    atomicAdd(&out[(size_t)(idx >> 2) * HD + col], w * (acc[mb][cb][q] + bdv));
                }
            }
        }
}

extern "C" void kernel_launch(void* const* d_in, const int* in_sizes, int n_in,
                              void* d_out, int out_size, void* d_ws, size_t ws_size,
                              hipStream_t stream)
{
    const float* x  = (const float*)d_in[0];
    const float* rw = (const float*)d_in[1];
    const float* rb = (const float*)d_in[2];
    const float* wg = (const float*)d_in[3];
    const float* bg = (const float*)d_in[4];
    const float* wu = (const float*)d_in[5];
    const float* bu = (const float*)d_in[6];
    const float* wd = (const float*)d_in[7];
    const float* bd = (const float*)d_in[8];
    float* out = (float*)d_out;

    char* ws = (char*)d_ws;
    int*   cnt  = (int*)(ws + 0);
    int*   offs = (int*)(ws + 256);
    float* topw = (float*)(ws + 1024);
    int*   list = (int*)(ws + 32768);
    unsigned short* act = (unsigned short*)(ws + 131072);            // 4096 x 2880 bf16 (23.6 MB)
    unsigned short* xbf = (unsigned short*)(ws + 131072 + (size_t)4096 * ID * 2);  // 1024 x 2880 bf16 (5.9 MB)

    hipLaunchKernelGGL(k_init, dim3(T_TOK * HD / 1024), dim3(256), 0, stream, out, cnt);
    hipLaunchKernelGGL(k_xbf, dim3(T_TOK * HD / (256 * 8)), dim3(256), 0, stream, x, xbf);
    hipLaunchKernelGGL(k_router, dim3(T_TOK), dim3(256), 0, stream, x, rw, rb, topw, cnt, list);
    hipLaunchKernelGGL(k_scan, dim3(1), dim3(64), 0, stream, cnt, offs);
    hipLaunchKernelGGL(k_gemm1, dim3(NB1), dim3(512), 0, stream,
                       xbf, wg, bg, wu, bu, cnt, offs, list, act);
    hipLaunchKernelGGL(k_gemm2, dim3(NB1), dim3(512), 0, stream,
                       act, wd, bd, topw, cnt, offs, list, out);
}

// Round 4
// 1379.651 us; speedup vs baseline: 1.3032x; 1.3032x over previous
//
#include <hip/hip_runtime.h>
#include <stdint.h>

#define T_TOK 1024
#define HD 2880
#define ID 2880
#define NE 16
#define NTOP 4

#define BM 128
#define BN 64
#define BK 64
#define NKT (HD / BK)        // 45
#define NIB (ID / BN)        // 45
#define NMB (T_TOK / BM)     // 8
#define NB1 (NE * NIB * NMB) // 5760

typedef short bf16x8 __attribute__((ext_vector_type(8)));
typedef float f32x4 __attribute__((ext_vector_type(4)));

// fp32 -> bf16 (RNE) via native __bf16 cast (v_cvt_pk_bf16_f32)
__device__ __forceinline__ uint4 pack8f(const float* v) {
    union { __bf16 b[8]; uint4 q; } p;
#pragma unroll
    for (int j = 0; j < 8; j++) p.b[j] = (__bf16)v[j];
    return p.q;
}
__device__ __forceinline__ unsigned short bf16bits(float f) {
    union { __bf16 b[2]; unsigned short u[2]; } p;
    p.b[0] = (__bf16)f;
    return p.u[0];
}

// ---------------- init: zero output + counts ----------------
__global__ __launch_bounds__(256) void k_init(float* __restrict__ out, int* __restrict__ cnt) {
    int i = blockIdx.x * 256 + threadIdx.x;
    ((float4*)out)[i] = make_float4(0.f, 0.f, 0.f, 0.f);
    if (blockIdx.x == 0 && threadIdx.x < NE) cnt[threadIdx.x] = 0;
}

// ---------------- x -> bf16 pre-pass ----------------
__global__ __launch_bounds__(256) void k_xbf(const float* __restrict__ x, unsigned short* __restrict__ xbf) {
    const size_t i = (size_t)blockIdx.x * 256 + threadIdx.x;   // 8 floats each
    float v[8];
    float4 a = ((const float4*)x)[i * 2];
    float4 b = ((const float4*)x)[i * 2 + 1];
    v[0] = a.x; v[1] = a.y; v[2] = a.z; v[3] = a.w;
    v[4] = b.x; v[5] = b.y; v[6] = b.z; v[7] = b.w;
    ((uint4*)xbf)[i] = pack8f(v);
}

// ---------------- router ----------------
__global__ __launch_bounds__(256) void k_router(
    const float* __restrict__ x, const float* __restrict__ rw, const float* __restrict__ rb,
    float* __restrict__ topw, int* __restrict__ cnt, int* __restrict__ list)
{
    const int t = blockIdx.x;
    const int tid = threadIdx.x;
    float acc[NE];
#pragma unroll
    for (int e = 0; e < NE; e++) acc[e] = 0.f;
    for (int c = tid; c < HD; c += 256) {
        float xv = x[(size_t)t * HD + c];
#pragma unroll
        for (int e = 0; e < NE; e++) acc[e] += xv * rw[(size_t)e * HD + c];
    }
    __shared__ float red[4][NE];
    const int lane = tid & 63, wv = tid >> 6;
#pragma unroll
    for (int e = 0; e < NE; e++) {
        float v = acc[e];
#pragma unroll
        for (int off = 32; off > 0; off >>= 1) v += __shfl_down(v, off, 64);
        if (lane == 0) red[wv][e] = v;
    }
    __syncthreads();
    if (tid == 0) {
        float p[NE];
        float mx = -1e30f;
        for (int e = 0; e < NE; e++) {
            float v = red[0][e] + red[1][e] + red[2][e] + red[3][e] + rb[e];
            p[e] = v; mx = fmaxf(mx, v);
        }
        for (int e = 0; e < NE; e++) p[e] = expf(p[e] - mx);
        int sel[NTOP]; float pw[NTOP]; float ssum = 0.f;
        for (int k = 0; k < NTOP; k++) {
            float best = -1.f; int bi = 0;
            for (int e = 0; e < NE; e++)
                if (p[e] > best) { best = p[e]; bi = e; }
            sel[k] = bi; pw[k] = best; ssum += best; p[bi] = -2.f;
        }
        for (int k = 0; k < NTOP; k++) {
            topw[t * NTOP + k] = pw[k] / ssum;
            int e = sel[k];
            int pos = atomicAdd(&cnt[e], 1);
            list[e * T_TOK + pos] = t * NTOP + k;
        }
    }
}

// ---------------- prefix scan ----------------
__global__ void k_scan(const int* __restrict__ cnt, int* __restrict__ offs) {
    if (threadIdx.x == 0 && blockIdx.x == 0) {
        int s = 0;
        for (int e = 0; e < NE; e++) { offs[e] = s; s += cnt[e]; }
        offs[NE] = s;
    }
}

// ---------------- GEMM1: A direct from global (bf16), W dbuf LDS, reg prefetch ----------------
__global__ __launch_bounds__(512, 4) void k_gemm1(
    const unsigned short* __restrict__ xbf,
    const float* __restrict__ wg, const float* __restrict__ bg,
    const float* __restrict__ wu, const float* __restrict__ bu,
    const int* __restrict__ cnt, const int* __restrict__ offs,
    const int* __restrict__ list,
    unsigned short* __restrict__ act)
{
    const int lin = blockIdx.x;
    const int logical = (lin & 7) * (NB1 / 8) + (lin >> 3);
    const int mblk = logical & 7;
    const int iblk = (logical >> 3) % NIB;
    const int e = logical / (NIB * NMB);

    const int count = cnt[e];
    const int m0 = mblk * BM;
    if (m0 >= count) return;
    const int mcount = min(BM, count - m0);
    const int i0 = iblk * BN;
    const int tid = threadIdx.x;

    __shared__ char sG[2][BN * BK * 2];   // 8 KB x2
    __shared__ char sU[2][BN * BK * 2];   // 8 KB x2
    __shared__ int lidx[BM];

    if (tid < BM) lidx[tid] = list[e * T_TOK + m0 + min(tid, mcount - 1)];

    // W staging: tid<256 -> gate, else up; per thread 16 strided floats
    const int wtid = tid & 255;
    const int wc = wtid & 63, whg = wtid >> 6;
    const float* wsrc = (tid < 256 ? wg : wu) + ((size_t)e * HD + whg * 16) * ID + i0 + wc;
    char* const wb0 = (tid < 256 ? sG[0] : sU[0]);
    char* const wb1 = (tid < 256 ? sG[1] : sU[1]);

    const int lane = tid & 63, wid = tid >> 6;
    const int wm = wid >> 1, wn = wid & 1;
    const int lr = lane & 15, lk = lane >> 4;

    float rwv[16];
#define LOADW1(kt_) { _Pragma("unroll") \
        for (int j_ = 0; j_ < 16; j_++) rwv[j_] = wsrc[(size_t)((kt_) * BK + j_) * ID]; }
#define STOREW1(b_) { \
        char* wd_ = (b_) ? wb1 : wb0; \
        *(uint4*)(wd_ + wc * 128 + (((whg * 2) ^ (wc & 7)) * 16)) = pack8f(rwv); \
        *(uint4*)(wd_ + wc * 128 + (((whg * 2 + 1) ^ (wc & 7)) * 16)) = pack8f(rwv + 8); }

    f32x4 accG[2][2], accU[2][2];
#pragma unroll
    for (int mb = 0; mb < 2; mb++)
#pragma unroll
        for (int cb = 0; cb < 2; cb++) {
            accG[mb][cb] = (f32x4){0.f, 0.f, 0.f, 0.f};
            accU[mb][cb] = (f32x4){0.f, 0.f, 0.f, 0.f};
        }

#define MFMA1(kt_) { \
        const char* cG = sG[(kt_) & 1]; \
        const char* cU = sU[(kt_) & 1]; \
        bf16x8 af[2][2]; \
        _Pragma("unroll") \
        for (int ks = 0; ks < 2; ks++) { \
            const int koff = (kt_) * BK + (ks * 4 + lk) * 8; \
            af[ks][0] = *(const bf16x8*)(arow0 + koff); \
            af[ks][1] = *(const bf16x8*)(arow1 + koff); \
        } \
        _Pragma("unroll") \
        for (int ks = 0; ks < 2; ks++) { \
            const int s = ks * 4 + lk; \
            _Pragma("unroll") \
            for (int cb = 0; cb < 2; cb++) { \
                const int ii = wn * 32 + cb * 16 + lr; \
                bf16x8 gf = *(const bf16x8*)(cG + ii * 128 + ((s ^ (ii & 7)) * 16)); \
                accG[0][cb] = __builtin_amdgcn_mfma_f32_16x16x32_bf16(af[ks][0], gf, accG[0][cb], 0, 0, 0); \
                accG[1][cb] = __builtin_amdgcn_mfma_f32_16x16x32_bf16(af[ks][1], gf, accG[1][cb], 0, 0, 0); \
                bf16x8 uf = *(const bf16x8*)(cU + ii * 128 + ((s ^ (ii & 7)) * 16)); \
                accU[0][cb] = __builtin_amdgcn_mfma_f32_16x16x32_bf16(af[ks][0], uf, accU[0][cb], 0, 0, 0); \
                accU[1][cb] = __builtin_amdgcn_mfma_f32_16x16x32_bf16(af[ks][1], uf, accU[1][cb], 0, 0, 0); \
            } \
        } }

    LOADW1(0);
    __syncthreads();   // lidx visible
    const unsigned short* arow0 = xbf + (size_t)(lidx[wm * 32 + lr] >> 2) * HD;
    const unsigned short* arow1 = xbf + (size_t)(lidx[wm * 32 + 16 + lr] >> 2) * HD;
    STOREW1(0);
    __syncthreads();

    for (int kt = 0; kt < NKT - 1; kt++) {
        LOADW1(kt + 1);            // in flight across the MFMA phase
        MFMA1(kt);
        STOREW1((kt + 1) & 1);     // safe: buf (kt+1)&1 was consumed in iter kt-1
        __syncthreads();
    }
    MFMA1(NKT - 1);
#undef LOADW1
#undef STOREW1
#undef MFMA1

    const int gbase = offs[e] + m0;
#pragma unroll
    for (int mb = 0; mb < 2; mb++)
#pragma unroll
        for (int cb = 0; cb < 2; cb++) {
            const int col = i0 + wn * 32 + cb * 16 + lr;
            const float bgv = bg[e * ID + col];
            const float buv = bu[e * ID + col];
#pragma unroll
            for (int q = 0; q < 4; q++) {
                const int r = wm * 32 + mb * 16 + lk * 4 + q;
                if (r < mcount) {
                    float gv = fminf(accG[mb][cb][q] + bgv, 7.0f);
                    float uv = fminf(fmaxf(accU[mb][cb][q] + buv, -7.0f), 7.0f);
                    float av = (uv + 1.0f) * (gv / (1.0f + __expf(-1.702f * gv)));
                    act[(size_t)(gbase + r) * ID + col] = bf16bits(av);
                }
            }
        }
}

// ---------------- GEMM2: A direct from act, W dbuf LDS, reg prefetch ----------------
__global__ __launch_bounds__(512, 4) void k_gemm2(
    const unsigned short* __restrict__ act,
    const float* __restrict__ wd, const float* __restrict__ bd,
    const float* __restrict__ topw,
    const int* __restrict__ cnt, const int* __restrict__ offs,
    const int* __restrict__ list,
    float* __restrict__ out)
{
    const int lin = blockIdx.x;
    const int logical = (lin & 7) * (NB1 / 8) + (lin >> 3);
    const int mblk = logical & 7;
    const int hblk = (logical >> 3) % NIB;
    const int e = logical / (NIB * NMB);

    const int count = cnt[e];
    const int m0 = mblk * BM;
    if (m0 >= count) return;
    const int mcount = min(BM, count - m0);
    const int h0 = hblk * BN;
    const int tid = threadIdx.x;
    const int gbase = offs[e] + m0;

    __shared__ char sW[2][BN * BK * 2];   // 8 KB x2
    __shared__ int lidx[BM];

    if (tid < BM) lidx[tid] = list[e * T_TOK + m0 + min(tid, mcount - 1)];

    const int wc = tid & 63, whg = tid >> 6;        // 8 k-groups of 8
    const float* wsrc = wd + (size_t)e * ID * HD + (size_t)(whg * 8) * HD + h0 + wc;

    const int lane = tid & 63, wid = tid >> 6;
    const int wm = wid >> 1, wn = wid & 1;
    const int lr = lane & 15, lk = lane >> 4;

    float rwv[8];
#define LOADW2(kt_) { _Pragma("unroll") \
        for (int j_ = 0; j_ < 8; j_++) rwv[j_] = wsrc[(size_t)((kt_) * BK + j_) * HD]; }
#define STOREW2(b_) { \
        *(uint4*)(sW[b_] + wc * 128 + ((whg ^ (wc & 7)) * 16)) = pack8f(rwv); }

    f32x4 acc[2][2];
#pragma unroll
    for (int mb = 0; mb < 2; mb++)
#pragma unroll
        for (int cb = 0; cb < 2; cb++) acc[mb][cb] = (f32x4){0.f, 0.f, 0.f, 0.f};

#define MFMA2(kt_) { \
        const char* cW = sW[(kt_) & 1]; \
        bf16x8 af[2][2]; \
        _Pragma("unroll") \
        for (int ks = 0; ks < 2; ks++) { \
            const int koff = (kt_) * BK + (ks * 4 + lk) * 8; \
            af[ks][0] = *(const bf16x8*)(arow0 + koff); \
            af[ks][1] = *(const bf16x8*)(arow1 + koff); \
        } \
        _Pragma("unroll") \
        for (int ks = 0; ks < 2; ks++) { \
            const int s = ks * 4 + lk; \
            _Pragma("unroll") \
            for (int cb = 0; cb < 2; cb++) { \
                const int ii = wn * 32 + cb * 16 + lr; \
                bf16x8 wf = *(const bf16x8*)(cW + ii * 128 + ((s ^ (ii & 7)) * 16)); \
                acc[0][cb] = __builtin_amdgcn_mfma_f32_16x16x32_bf16(af[ks][0], wf, acc[0][cb], 0, 0, 0); \
                acc[1][cb] = __builtin_amdgcn_mfma_f32_16x16x32_bf16(af[ks][1], wf, acc[1][cb], 0, 0, 0); \
            } \
        } }

    LOADW2(0);
    __syncthreads();   // lidx visible
    const int r0 = gbase + min(wm * 32 + lr, mcount - 1);
    const int r1 = gbase + min(wm * 32 + 16 + lr, mcount - 1);
    const unsigned short* arow0 = act + (size_t)r0 * ID;
    const unsigned short* arow1 = act + (size_t)r1 * ID;
    STOREW2(0);
    __syncthreads();

    for (int kt = 0; kt < NKT - 1; kt++) {
        LOADW2(kt + 1);
        MFMA2(kt);
        STOREW2((kt + 1) & 1);
        __syncthreads();
    }
    MFMA2(NKT - 1);
#undef LOADW2
#undef STOREW2
#undef MFMA2

#pragma unroll
    for (int mb = 0; mb < 2; mb++)
#pragma unroll
        for (int cb = 0; cb < 2; cb++) {
            const int col = h0 + wn * 32 + cb * 16 + lr;
            const float bdv = bd[e * HD + col];
#pragma unroll
            for (int q = 0; q < 4; q++) {
                const int r = wm * 32 + mb * 16 + lk * 4 + q;
                if (r < mcount) {
                    int idx = lidx[r];
                    float w = topw[idx];
                    atomicAdd(&out[(size_t)(idx >> 2) * HD + col], w * (acc[mb][cb][q] + bdv));
                }
            }
        }
}

extern "C" void kernel_launch(void* const* d_in, const int* in_sizes, int n_in,
                              void* d_out, int out_size, void* d_ws, size_t ws_size,
                              hipStream_t stream)
{
    const float* x  = (const float*)d_in[0];
    const float* rw = (const float*)d_in[1];
    const float* rb = (const float*)d_in[2];
    const float* wg = (const float*)d_in[3];
    const float* bg = (const float*)d_in[4];
    const float* wu = (const float*)d_in[5];
    const float* bu = (const float*)d_in[6];
    const float* wd = (const float*)d_in[7];
    const float* bd = (const float*)d_in[8];
    float* out = (float*)d_out;

    char* ws = (char*)d_ws;
    int*   cnt  = (int*)(ws + 0);
    int*   offs = (int*)(ws + 256);
    float* topw = (float*)(ws + 1024);
    int*   list = (int*)(ws + 32768);
    unsigned short* act = (unsigned short*)(ws + 131072);            // 4096 x 2880 bf16 (23.6 MB)
    unsigned short* xbf = (unsigned short*)(ws + 131072 + (size_t)4096 * ID * 2);  // 1024 x 2880 bf16 (5.9 MB)

    hipLaunchKernelGGL(k_init, dim3(T_TOK * HD / 1024), dim3(256), 0, stream, out, cnt);
    hipLaunchKernelGGL(k_xbf, dim3(T_TOK * HD / (256 * 8)), dim3(256), 0, stream, x, xbf);
    hipLaunchKernelGGL(k_router, dim3(T_TOK), dim3(256), 0, stream, x, rw, rb, topw, cnt, list);
    hipLaunchKernelGGL(k_scan, dim3(1), dim3(64), 0, stream, cnt, offs);
    hipLaunchKernelGGL(k_gemm1, dim3(NB1), dim3(512), 0, stream,
                       xbf, wg, bg, wu, bu, cnt, offs, list, act);
    hipLaunchKernelGGL(k_gemm2, dim3(NB1), dim3(512), 0, stream,
                       act, wd, bd, topw, cnt, offs, list, out);
}